// Round 4
// baseline (6356.497 us; speedup 1.0000x reference)
//
#include <hip/hip_runtime.h>
#include <hip/hip_bf16.h>

#define SEQ   256
#define BATCH 256
#define KDIM  1024
#define ODIM  1024

typedef __bf16 bf16_t;
typedef bf16_t bf16x8 __attribute__((ext_vector_type(8)));
typedef float  f32x4  __attribute__((ext_vector_type(4)));
typedef unsigned long long u64;

#define MFMA16 __builtin_amdgcn_mfma_f32_16x16x32_bf16
#define AGT    __HIP_MEMORY_SCOPE_AGENT

static __device__ __forceinline__ bf16x8 cvt8(float4 a, float4 b) {
    return (bf16x8){(bf16_t)a.x, (bf16_t)a.y, (bf16_t)a.z, (bf16_t)a.w,
                    (bf16_t)b.x, (bf16_t)b.y, (bf16_t)b.z, (bf16_t)b.w};
}
static __device__ __forceinline__ u64 pack4(f32x4 v) {
    union { bf16_t h[4]; u64 q; } u;
    u.h[0] = (bf16_t)v[0]; u.h[1] = (bf16_t)v[1];
    u.h[2] = (bf16_t)v[2]; u.h[3] = (bf16_t)v[3];
    return u.q;
}

// ---------------------------------------------------------------------------
// Persistent GRU. 256 blocks (1/CU) x 256 threads (4 waves).
// Block (mg=blockIdx&7, nt=blockIdx>>3) owns output rows mg*32..+32, cols
// nt*32..+32 for all 256 timesteps. Wave kq = tid>>6 owns K-quarter.
// Weights: Wrx,Wrh,Wux,Wuh,Wcx as MFMA B-fragments in VGPRs/AGPRs (320/wave;
// fits the 512 unified budget at 1 wave/SIMD), Wch as fragments in LDS (64 KB).
// LDS total 102,912 B -- deliberately < 131,072 B (the round-1-proven bound;
// 135,680 B appears to make cooperative-launch validation reject the grid).
// Sync: per-block flags; RELEASE store after the post-store __syncthreads,
// relaxed AGENT polling + one ACQUIRE load before the h-phase (round-1 idiom).
// x-phase MFMAs (no h dependency) run before the flag wait to hide skew.
// ---------------------------------------------------------------------------
__global__ __launch_bounds__(256, 1) void gru_persistent(
    const float* __restrict__ x, const float* __restrict__ h0,
    float* __restrict__ hseq, float* __restrict__ hlast,
    bf16_t* __restrict__ hb, unsigned* __restrict__ flags,
    const float* __restrict__ Wrx, const float* __restrict__ Wrh,
    const float* __restrict__ Wux, const float* __restrict__ Wuh,
    const float* __restrict__ Wcx, const float* __restrict__ Wch,
    const float* __restrict__ brx, const float* __restrict__ brh,
    const float* __restrict__ bux, const float* __restrict__ buh,
    const float* __restrict__ bcx, const float* __restrict__ bch)
{
    __shared__ bf16x8 sWch[4096];      // 64 KB: [nh][kq][ks][quad][lr] fragments
    __shared__ f32x4  sRed[2048];      // 32 KB: [half][slot16][lane64]
    __shared__ float  sHf[32][36];     // 4.5 KB: output retile staging

    const int tid    = threadIdx.x;
    const int mg     = blockIdx.x & 7;
    const int nt     = blockIdx.x >> 3;
    const int m_base = mg * 32;
    const int n_base = nt * 32;
    const int lane   = tid & 63;
    const int kq     = tid >> 6;       // wave = K-quarter
    const int lr     = lane & 15;
    const int quad   = lane >> 4;

    // ---- weights -> registers (5 mats x 2 n-halves x 8 k-steps) ----
    bf16x8 wreg[5][2][8];
    #define LOADW(wi, SRC) { \
        _Pragma("unroll") \
        for (int nh = 0; nh < 2; ++nh) { \
            const float* s_ = SRC + (size_t)(n_base + nh * 16 + lr) * KDIM + kq * 256 + quad * 8; \
            _Pragma("unroll") \
            for (int ks = 0; ks < 8; ++ks) \
                wreg[wi][nh][ks] = cvt8(*(const float4*)(s_ + ks * 32), \
                                        *(const float4*)(s_ + ks * 32 + 4)); \
        } }
    LOADW(0, Wrx) LOADW(1, Wrh) LOADW(2, Wux) LOADW(3, Wuh) LOADW(4, Wcx)
    #undef LOADW

    // ---- Wch -> LDS fragments ----
    #pragma unroll
    for (int j = 0; j < 16; ++j) {
        const int f    = tid + 256 * j;
        const int flr  = f & 15;
        const int fq   = (f >> 4) & 3;
        const int fks  = (f >> 6) & 7;
        const int fkq  = (f >> 9) & 3;
        const int fnh  = (f >> 11) & 1;
        const float* s_ = Wch + (size_t)(n_base + fnh * 16 + flr) * KDIM
                              + fkq * 256 + fks * 32 + fq * 8;
        sWch[f] = cvt8(*(const float4*)s_, *(const float4*)(s_ + 4));
    }

    // ---- epilogue mapping: thread -> 4 output rows x 1 col ----
    const int emh   = tid >> 7;
    const int enh   = (tid >> 6) & 1;
    const int el    = tid & 63;
    const int eq    = el >> 4;
    const int elr   = el & 15;
    const int lrow0 = emh * 16 + eq * 4;
    const int lcol  = enh * 16 + elr;
    const int oc    = n_base + lcol;
    const int orow0 = m_base + lrow0;
    const float vbrx = brx[oc], vbrh = brh[oc];
    const float vbux = bux[oc], vbuh = buh[oc];
    const float vbcx = bcx[oc], vbch = bch[oc];

    float hk[4];
    #pragma unroll
    for (int r = 0; r < 4; ++r) hk[r] = h0[(size_t)(orow0 + r) * ODIM + oc];

    // ---- stage h0 -> hb[0] (own 32x32 tile) via LDS retile, plain stores ----
    #pragma unroll
    for (int r = 0; r < 4; ++r) sHf[lrow0 + r][lcol] = hk[r];
    __syncthreads();
    const int rr = tid >> 3;
    const int cc = (tid & 7) * 4;
    {
        f32x4 v = *(const f32x4*)&sHf[rr][cc];
        *(u64*)(hb + (size_t)(m_base + rr) * ODIM + n_base + cc) = pack4(v);
    }
    __syncthreads();   // drains every wave's stores before the release
    if (tid == 0)
        __hip_atomic_store(flags + mg * 32 + nt, 1u, __ATOMIC_RELEASE, AGT);

    unsigned* fp      = flags + mg * 32 + (lane & 31);
    const size_t kcol = (size_t)(kq * 256 + quad * 8);

    for (int t = 0; t < SEQ; ++t) {
        f32x4 acc[4][2][2];   // [gate: r,z,cx,ch][m-half][n-half]
        #pragma unroll
        for (int g = 0; g < 4; ++g)
            #pragma unroll
            for (int mh = 0; mh < 2; ++mh)
                #pragma unroll
                for (int nh = 0; nh < 2; ++nh)
                    acc[g][mh][nh] = (f32x4){0.f, 0.f, 0.f, 0.f};

        // ---------------- x phase (no h dependency: overlaps group skew) -----
        {
            const float* xt = x + (size_t)t * BATCH * KDIM;
            #pragma unroll
            for (int ks = 0; ks < 8; ++ks) {
                const float* p0 = xt + (size_t)(m_base + lr) * KDIM + kcol + ks * 32;
                const float* p1 = p0 + 16 * KDIM;
                const bf16x8 ax0 = cvt8(*(const float4*)p0, *(const float4*)(p0 + 4));
                const bf16x8 ax1 = cvt8(*(const float4*)p1, *(const float4*)(p1 + 4));
                acc[0][0][0] = MFMA16(ax0, wreg[0][0][ks], acc[0][0][0], 0, 0, 0);
                acc[0][0][1] = MFMA16(ax0, wreg[0][1][ks], acc[0][0][1], 0, 0, 0);
                acc[0][1][0] = MFMA16(ax1, wreg[0][0][ks], acc[0][1][0], 0, 0, 0);
                acc[0][1][1] = MFMA16(ax1, wreg[0][1][ks], acc[0][1][1], 0, 0, 0);
                acc[1][0][0] = MFMA16(ax0, wreg[2][0][ks], acc[1][0][0], 0, 0, 0);
                acc[1][0][1] = MFMA16(ax0, wreg[2][1][ks], acc[1][0][1], 0, 0, 0);
                acc[1][1][0] = MFMA16(ax1, wreg[2][0][ks], acc[1][1][0], 0, 0, 0);
                acc[1][1][1] = MFMA16(ax1, wreg[2][1][ks], acc[1][1][1], 0, 0, 0);
                acc[2][0][0] = MFMA16(ax0, wreg[4][0][ks], acc[2][0][0], 0, 0, 0);
                acc[2][0][1] = MFMA16(ax0, wreg[4][1][ks], acc[2][0][1], 0, 0, 0);
                acc[2][1][0] = MFMA16(ax1, wreg[4][0][ks], acc[2][1][0], 0, 0, 0);
                acc[2][1][1] = MFMA16(ax1, wreg[4][1][ks], acc[2][1][1], 0, 0, 0);
            }
        }

        // ---------------- wait: h(t) ready; ACQUIRE = cache invalidate --------
        if (tid < 64) {
            const unsigned tgt = (unsigned)(t + 1);
            while (true) {
                unsigned v = __hip_atomic_load(fp, __ATOMIC_RELAXED, AGT);
                if (__all((int)(v >= tgt))) break;
                __builtin_amdgcn_s_sleep(2);
            }
            if (lane == 0)
                (void)__hip_atomic_load(fp, __ATOMIC_ACQUIRE, AGT);
        }
        __syncthreads();

        // ---------------- h phase: ordinary loads, then 96 MFMAs --------------
        {
            const bf16_t* hsrc = hb + (size_t)(t & 1) * ((size_t)BATCH * ODIM);
            #pragma unroll
            for (int mh = 0; mh < 2; ++mh) {
                const bf16_t* hp = hsrc + (size_t)(m_base + mh * 16 + lr) * KDIM + kcol;
                #pragma unroll
                for (int ks = 0; ks < 8; ++ks) {
                    const bf16x8 ah  = *(const bf16x8*)(hp + ks * 32);
                    const bf16x8 wc0 = sWch[kq * 512 + ks * 64 + lane];
                    const bf16x8 wc1 = sWch[2048 + kq * 512 + ks * 64 + lane];
                    acc[0][mh][0] = MFMA16(ah, wreg[1][0][ks], acc[0][mh][0], 0, 0, 0);
                    acc[0][mh][1] = MFMA16(ah, wreg[1][1][ks], acc[0][mh][1], 0, 0, 0);
                    acc[1][mh][0] = MFMA16(ah, wreg[3][0][ks], acc[1][mh][0], 0, 0, 0);
                    acc[1][mh][1] = MFMA16(ah, wreg[3][1][ks], acc[1][mh][1], 0, 0, 0);
                    acc[3][mh][0] = MFMA16(ah, wc0,            acc[3][mh][0], 0, 0, 0);
                    acc[3][mh][1] = MFMA16(ah, wc1,            acc[3][mh][1], 0, 0, 0);
                }
            }
        }

        // ---------------- cross-wave K reduction (two-stage, 32 KB) -----------
        // stage A: waves 2,3 deposit partials
        if (kq >= 2) {
            #pragma unroll
            for (int g = 0; g < 4; ++g)
                #pragma unroll
                for (int mh = 0; mh < 2; ++mh)
                    #pragma unroll
                    for (int nh = 0; nh < 2; ++nh)
                        sRed[(kq - 2) * 1024 + (g * 4 + mh * 2 + nh) * 64 + lane]
                            = acc[g][mh][nh];
        }
        __syncthreads();
        // stage B: waves 0,1 fold their partials on top (per-(slot,lane) owner)
        if (kq < 2) {
            #pragma unroll
            for (int g = 0; g < 4; ++g)
                #pragma unroll
                for (int mh = 0; mh < 2; ++mh)
                    #pragma unroll
                    for (int nh = 0; nh < 2; ++nh) {
                        const int i2 = kq * 1024 + (g * 4 + mh * 2 + nh) * 64 + lane;
                        sRed[i2] = sRed[i2] + acc[g][mh][nh];
                    }
        }
        __syncthreads();

        f32x4 sv[4];
        #pragma unroll
        for (int g = 0; g < 4; ++g) {
            const int s = (g * 4 + emh * 2 + enh) * 64 + el;
            sv[g] = sRed[s] + sRed[1024 + s];
        }

        // ---------------- gates (h_old register-resident) ----------------
        #pragma unroll
        for (int r = 0; r < 4; ++r) {
            const float pre_r = sv[0][r] + vbrx + vbrh;
            const float rg    = 1.f / (1.f + __expf(-pre_r));
            const float pre_z = sv[1][r] + vbux + vbuh;
            const float zg    = 1.f / (1.f + __expf(-pre_z));
            const float pre_n = sv[2][r] + vbcx + rg * (sv[3][r] + vbch);
            const float ng    = tanhf(pre_n);
            hk[r] = (1.f - zg) * ng + zg * hk[r];
            sHf[lrow0 + r][lcol] = hk[r];
        }
        __syncthreads();

        // ---------------- retiled stores: hseq (NT f32x4), hb (plain u64) -----
        {
            bf16_t* hdst = hb + (size_t)((t + 1) & 1) * ((size_t)BATCH * ODIM);
            const f32x4 v = *(const f32x4*)&sHf[rr][cc];
            const size_t go = (size_t)(m_base + rr) * ODIM + n_base + cc;
            float* hs = hseq + (size_t)t * ((size_t)BATCH * ODIM) + go;
            __builtin_nontemporal_store(v, (f32x4*)hs);
            *(u64*)(hdst + go) = pack4(v);
            if (t == SEQ - 1)
                __builtin_nontemporal_store(v, (f32x4*)(hlast + go));
        }
        __syncthreads();   // drains every wave's stores before the release
        if (tid == 0 && t < SEQ - 1)
            __hip_atomic_store(flags + mg * 32 + nt, (unsigned)(t + 2),
                               __ATOMIC_RELEASE, AGT);
    }
}

// ---------------------------------------------------------------------------
extern "C" void kernel_launch(void* const* d_in, const int* in_sizes, int n_in,
                              void* d_out, int out_size, void* d_ws, size_t ws_size,
                              hipStream_t stream)
{
    (void)in_sizes; (void)n_in; (void)out_size; (void)ws_size;
    const float* x   = (const float*)d_in[0];
    const float* h0  = (const float*)d_in[1];
    const float* Wrx = (const float*)d_in[2];
    const float* brx = (const float*)d_in[3];
    const float* Wrh = (const float*)d_in[4];
    const float* brh = (const float*)d_in[5];
    const float* Wux = (const float*)d_in[6];
    const float* bux = (const float*)d_in[7];
    const float* Wuh = (const float*)d_in[8];
    const float* buh = (const float*)d_in[9];
    const float* Wcx = (const float*)d_in[10];
    const float* bcx = (const float*)d_in[11];
    const float* Wch = (const float*)d_in[12];
    const float* bch = (const float*)d_in[13];

    float* hseq  = (float*)d_out;
    float* hlast = hseq + (size_t)SEQ * BATCH * ODIM;

    // ws layout: [0,4K) flags | [4K, 4K+1MB) h bf16 ping-pong
    unsigned* flags = (unsigned*)d_ws;
    bf16_t*   hb    = (bf16_t*)((char*)d_ws + 4096);

    hipMemsetAsync(d_ws, 0, 4096, stream);

    void* args[] = {
        (void*)&x, (void*)&h0, (void*)&hseq, (void*)&hlast,
        (void*)&hb, (void*)&flags,
        (void*)&Wrx, (void*)&Wrh, (void*)&Wux, (void*)&Wuh, (void*)&Wcx, (void*)&Wch,
        (void*)&brx, (void*)&brh, (void*)&bux, (void*)&buh, (void*)&bcx, (void*)&bch };

    hipError_t err = hipLaunchCooperativeKernel((void*)gru_persistent,
                                                dim3(256), dim3(256), args, 0, stream);
    if (err != hipSuccess) {
        // Validation rejected the cooperative launch (nothing was enqueued).
        // 256 blocks at 1 block/CU on 256 CUs are co-resident anyway, and the
        // flag protocol needs no grid.sync -- plain launch is safe.
        (void)hipGetLastError();
        gru_persistent<<<dim3(256), dim3(256), 0, stream>>>(
            x, h0, hseq, hlast, hb, flags,
            Wrx, Wrh, Wux, Wuh, Wcx, Wch,
            brx, brh, bux, buh, bcx, bch);
    }
}

// Round 5
// 5204.936 us; speedup vs baseline: 1.2212x; 1.2212x over previous
//
#include <hip/hip_runtime.h>
#include <hip/hip_bf16.h>

#define SEQ   256
#define BATCH 256
#define KDIM  1024
#define ODIM  1024

typedef __bf16 bf16_t;
typedef bf16_t bf16x8 __attribute__((ext_vector_type(8)));
typedef float  f32x4  __attribute__((ext_vector_type(4)));
typedef float  f32x2  __attribute__((ext_vector_type(2)));
typedef unsigned long long u64;

#define MFMA16 __builtin_amdgcn_mfma_f32_16x16x32_bf16
#define AGT    __HIP_MEMORY_SCOPE_AGENT

static __device__ __forceinline__ bf16x8 cvt8(float4 a, float4 b) {
    return (bf16x8){(bf16_t)a.x, (bf16_t)a.y, (bf16_t)a.z, (bf16_t)a.w,
                    (bf16_t)b.x, (bf16_t)b.y, (bf16_t)b.z, (bf16_t)b.w};
}
static __device__ __forceinline__ bf16x8 mk8(u64 lo, u64 hi) {
    union { u64 q[2]; bf16x8 v; } u; u.q[0] = lo; u.q[1] = hi; return u.v;
}
static __device__ __forceinline__ unsigned pack2(f32x2 v) {
    union { bf16_t h[2]; unsigned u; } x;
    x.h[0] = (bf16_t)v[0]; x.h[1] = (bf16_t)v[1];
    return x.u;
}

// ---------------------------------------------------------------------------
// Persistent GRU. 256 blocks (1/CU) x 512 threads (8 waves, 2/SIMD).
// Block (mg=blockIdx&7, nt=blockIdx>>3) owns output rows mg*32..+32, cols
// nt*32..+32 for all 256 timesteps. Wave wv: nh = wv&1 (n-half), kq = wv>>1
// (K-quarter). Per-wave weights: Wrx,Wrh,Wux,Wuh,Wcx fragments for (nh,kq) =
// 160 VGPRs (fits 256-reg cap at 2 waves/SIMD, no spill); Wch in LDS (64 KB).
// Cross-block h exchange: relaxed AGENT-scope atomics (sc1 -> MALL-coherent,
// bypass stale L1/L2). NO buffer_wbl2 / buffer_inv in the loop. Producer:
// data stores -> vmcnt(0) -> barrier -> flag store. Consumer: poll flag ->
// barrier -> sc1 loads. x-phase MFMAs run before the poll to hide skew.
// ---------------------------------------------------------------------------
__global__ __launch_bounds__(512, 2) void gru_persistent(
    const float* __restrict__ x, const float* __restrict__ h0,
    float* __restrict__ hseq, float* __restrict__ hlast,
    bf16_t* __restrict__ hb, unsigned* __restrict__ flags,
    const float* __restrict__ Wrx, const float* __restrict__ Wrh,
    const float* __restrict__ Wux, const float* __restrict__ Wuh,
    const float* __restrict__ Wcx, const float* __restrict__ Wch,
    const float* __restrict__ brx, const float* __restrict__ brh,
    const float* __restrict__ bux, const float* __restrict__ buh,
    const float* __restrict__ bcx, const float* __restrict__ bch)
{
    __shared__ bf16x8 sWch[4096];      // 64 KB: [nh][kq][ks][quad][lr] fragments
    __shared__ f32x4  sRed[2048];      // 32 KB: [nh][slot2][g*2+mh][lane]
    __shared__ float  sHf[32][34];     // 4.25 KB: output retile staging

    const int tid    = threadIdx.x;
    const int mg     = blockIdx.x & 7;
    const int nt     = blockIdx.x >> 3;
    const int m_base = mg * 32;
    const int n_base = nt * 32;
    const int lane   = tid & 63;
    const int wv     = tid >> 6;
    const int nh     = wv & 1;         // n-half this wave computes
    const int kq     = wv >> 1;        // K-quarter this wave contracts
    const int lr     = lane & 15;
    const int quad   = lane >> 4;

    // ---- weights -> registers (5 mats x 8 k-steps for this wave's (nh,kq)) --
    bf16x8 wreg[5][8];
    {
        const size_t wrow = (size_t)(n_base + nh * 16 + lr) * KDIM + kq * 256 + quad * 8;
        #define LOADW(wi, SRC) { \
            const float* s_ = SRC + wrow; \
            _Pragma("unroll") \
            for (int ks = 0; ks < 8; ++ks) \
                wreg[wi][ks] = cvt8(*(const float4*)(s_ + ks * 32), \
                                    *(const float4*)(s_ + ks * 32 + 4)); \
        }
        LOADW(0, Wrx) LOADW(1, Wrh) LOADW(2, Wux) LOADW(3, Wuh) LOADW(4, Wcx)
        #undef LOADW
    }

    // ---- Wch -> LDS fragments ----
    #pragma unroll
    for (int j = 0; j < 8; ++j) {
        const int f    = tid + 512 * j;
        const int flr  = f & 15;
        const int fq   = (f >> 4) & 3;
        const int fks  = (f >> 6) & 7;
        const int fkq  = (f >> 9) & 3;
        const int fnh  = (f >> 11) & 1;
        const float* s_ = Wch + (size_t)(n_base + fnh * 16 + flr) * KDIM
                              + fkq * 256 + fks * 32 + fq * 8;
        sWch[f] = cvt8(*(const float4*)s_, *(const float4*)(s_ + 4));
    }

    // ---- epilogue mapping: thread -> 2 output rows x 1 col ----
    const int elr   = tid & 15;
    const int equad = (tid >> 4) & 3;
    const int emh   = (tid >> 6) & 1;
    const int enh   = (tid >> 7) & 1;
    const int epair = (tid >> 8) & 1;
    const int lcol  = enh * 16 + elr;
    const int lrow0 = emh * 16 + equad * 4 + epair * 2;
    const int oc    = n_base + lcol;
    const int orow0 = m_base + lrow0;
    const float vbrx = brx[oc], vbrh = brh[oc];
    const float vbux = bux[oc], vbuh = buh[oc];
    const float vbcx = bcx[oc], vbch = bch[oc];

    float hk0 = h0[(size_t)orow0 * ODIM + oc];
    float hk1 = h0[(size_t)(orow0 + 1) * ODIM + oc];

    // ---- retile mapping: thread -> 1 row x 2 cols (f32x2 / u32 granules) ----
    const int rr = tid >> 4;           // row 0..31
    const int cc = (tid & 15) * 2;     // col pair

    // ---- stage h0 -> hb[0] via LDS retile + sc1 stores ----
    sHf[lrow0][lcol]     = hk0;
    sHf[lrow0 + 1][lcol] = hk1;
    __syncthreads();
    {
        const f32x2 v = *(const f32x2*)&sHf[rr][cc];
        __hip_atomic_store((unsigned*)(hb + (size_t)(m_base + rr) * ODIM + n_base + cc),
                           pack2(v), __ATOMIC_RELAXED, AGT);
    }
    asm volatile("s_waitcnt vmcnt(0)" ::: "memory");
    __syncthreads();
    if (tid == 0)
        __hip_atomic_store(flags + mg * 32 + nt, 1u, __ATOMIC_RELAXED, AGT);

    unsigned* fp      = flags + mg * 32 + (lane & 31);
    const size_t kcol = (size_t)(kq * 256 + quad * 8);

    for (int t = 0; t < SEQ; ++t) {
        f32x4 acc[4][2];   // [gate: r,z,cx,ch][m-half] for this wave's n-half
        #pragma unroll
        for (int g = 0; g < 4; ++g) {
            acc[g][0] = (f32x4){0.f, 0.f, 0.f, 0.f};
            acc[g][1] = (f32x4){0.f, 0.f, 0.f, 0.f};
        }

        // ---------------- x phase (no h dependency: overlaps group skew) -----
        {
            const float* xt = x + (size_t)t * BATCH * KDIM;
            #pragma unroll
            for (int mh = 0; mh < 2; ++mh) {
                const float* xp = xt + (size_t)(m_base + mh * 16 + lr) * KDIM + kcol;
                #pragma unroll
                for (int ks = 0; ks < 8; ++ks) {
                    const bf16x8 ax = cvt8(*(const float4*)(xp + ks * 32),
                                           *(const float4*)(xp + ks * 32 + 4));
                    acc[0][mh] = MFMA16(ax, wreg[0][ks], acc[0][mh], 0, 0, 0);
                    acc[1][mh] = MFMA16(ax, wreg[2][ks], acc[1][mh], 0, 0, 0);
                    acc[2][mh] = MFMA16(ax, wreg[4][ks], acc[2][mh], 0, 0, 0);
                }
            }
        }

        // ---------------- wait: h(t) ready (32 per-block flags via MALL) ------
        if (tid < 64) {
            const unsigned tgt = (unsigned)(t + 1);
            while (true) {
                unsigned v = __hip_atomic_load(fp, __ATOMIC_RELAXED, AGT);
                if (__all((int)(v >= tgt))) break;
                __builtin_amdgcn_s_sleep(1);
            }
        }
        asm volatile("" ::: "memory");
        __syncthreads();

        // ---------------- h phase: sc1 loads (MALL), 48 MFMAs/wave ------------
        {
            const bf16_t* hsrc = hb + (size_t)(t & 1) * ((size_t)BATCH * ODIM);
            #pragma unroll
            for (int mh = 0; mh < 2; ++mh) {
                const bf16_t* hp = hsrc + (size_t)(m_base + mh * 16 + lr) * KDIM + kcol;
                #pragma unroll
                for (int g2 = 0; g2 < 2; ++g2) {
                    u64 lo[4], hi[4];
                    #pragma unroll
                    for (int j = 0; j < 4; ++j) {
                        const u64* p = (const u64*)(hp + (g2 * 4 + j) * 32);
                        lo[j] = __hip_atomic_load(p,     __ATOMIC_RELAXED, AGT);
                        hi[j] = __hip_atomic_load(p + 1, __ATOMIC_RELAXED, AGT);
                    }
                    #pragma unroll
                    for (int j = 0; j < 4; ++j) {
                        const int ks = g2 * 4 + j;
                        const bf16x8 ah = mk8(lo[j], hi[j]);
                        const bf16x8 wc = sWch[nh * 2048 + kq * 512 + ks * 64 + lane];
                        acc[0][mh] = MFMA16(ah, wreg[1][ks], acc[0][mh], 0, 0, 0);
                        acc[1][mh] = MFMA16(ah, wreg[3][ks], acc[1][mh], 0, 0, 0);
                        acc[3][mh] = MFMA16(ah, wc,          acc[3][mh], 0, 0, 0);
                    }
                }
            }
        }

        // ---------------- cross-wave K reduction (two-stage, 32 KB) -----------
        if (kq >= 2) {
            #pragma unroll
            for (int g = 0; g < 4; ++g)
                #pragma unroll
                for (int mh = 0; mh < 2; ++mh)
                    sRed[nh * 1024 + (kq - 2) * 512 + (g * 2 + mh) * 64 + lane]
                        = acc[g][mh];
        }
        __syncthreads();
        if (kq < 2) {
            #pragma unroll
            for (int g = 0; g < 4; ++g)
                #pragma unroll
                for (int mh = 0; mh < 2; ++mh) {
                    const int i2 = nh * 1024 + kq * 512 + (g * 2 + mh) * 64 + lane;
                    sRed[i2] = sRed[i2] + acc[g][mh];
                }
        }
        __syncthreads();

        float s0v[4], s1v[4];
        #pragma unroll
        for (int g = 0; g < 4; ++g) {
            const int idx = (g * 2 + emh) * 64 + equad * 16 + elr;
            const f32x4 v = sRed[enh * 1024 + idx] + sRed[enh * 1024 + 512 + idx];
            s0v[g] = epair ? v[2] : v[0];
            s1v[g] = epair ? v[3] : v[1];
        }

        // ---------------- gates (h_old register-resident) ----------------
        {
            const float pre_r = s0v[0] + vbrx + vbrh;
            const float rg    = 1.f / (1.f + __expf(-pre_r));
            const float pre_z = s0v[1] + vbux + vbuh;
            const float zg    = 1.f / (1.f + __expf(-pre_z));
            const float pre_n = s0v[2] + vbcx + rg * (s0v[3] + vbch);
            const float ng    = tanhf(pre_n);
            hk0 = (1.f - zg) * ng + zg * hk0;
            sHf[lrow0][lcol] = hk0;
        }
        {
            const float pre_r = s1v[0] + vbrx + vbrh;
            const float rg    = 1.f / (1.f + __expf(-pre_r));
            const float pre_z = s1v[1] + vbux + vbuh;
            const float zg    = 1.f / (1.f + __expf(-pre_z));
            const float pre_n = s1v[2] + vbcx + rg * (s1v[3] + vbch);
            const float ng    = tanhf(pre_n);
            hk1 = (1.f - zg) * ng + zg * hk1;
            sHf[lrow0 + 1][lcol] = hk1;
        }
        __syncthreads();

        // ---------------- retiled stores: hseq (NT f32x2), hb (sc1 u32) -------
        {
            bf16_t* hdst = hb + (size_t)((t + 1) & 1) * ((size_t)BATCH * ODIM);
            const f32x2 v   = *(const f32x2*)&sHf[rr][cc];
            const size_t go = (size_t)(m_base + rr) * ODIM + n_base + cc;
            __builtin_nontemporal_store(v, (f32x2*)(hseq + (size_t)t * ((size_t)BATCH * ODIM) + go));
            __hip_atomic_store((unsigned*)(hdst + go), pack2(v), __ATOMIC_RELAXED, AGT);
            if (t == SEQ - 1)
                __builtin_nontemporal_store(v, (f32x2*)(hlast + go));
        }
        asm volatile("s_waitcnt vmcnt(0)" ::: "memory");
        __syncthreads();
        if (tid == 0 && t < SEQ - 1)
            __hip_atomic_store(flags + mg * 32 + nt, (unsigned)(t + 2),
                               __ATOMIC_RELAXED, AGT);
    }
}

// ---------------------------------------------------------------------------
extern "C" void kernel_launch(void* const* d_in, const int* in_sizes, int n_in,
                              void* d_out, int out_size, void* d_ws, size_t ws_size,
                              hipStream_t stream)
{
    (void)in_sizes; (void)n_in; (void)out_size; (void)ws_size;
    const float* x   = (const float*)d_in[0];
    const float* h0  = (const float*)d_in[1];
    const float* Wrx = (const float*)d_in[2];
    const float* brx = (const float*)d_in[3];
    const float* Wrh = (const float*)d_in[4];
    const float* brh = (const float*)d_in[5];
    const float* Wux = (const float*)d_in[6];
    const float* bux = (const float*)d_in[7];
    const float* Wuh = (const float*)d_in[8];
    const float* buh = (const float*)d_in[9];
    const float* Wcx = (const float*)d_in[10];
    const float* bcx = (const float*)d_in[11];
    const float* Wch = (const float*)d_in[12];
    const float* bch = (const float*)d_in[13];

    float* hseq  = (float*)d_out;
    float* hlast = hseq + (size_t)SEQ * BATCH * ODIM;

    // ws layout: [0,4K) flags | [4K, 4K+1MB) h bf16 ping-pong
    unsigned* flags = (unsigned*)d_ws;
    bf16_t*   hb    = (bf16_t*)((char*)d_ws + 4096);

    hipMemsetAsync(d_ws, 0, 4096, stream);

    void* args[] = {
        (void*)&x, (void*)&h0, (void*)&hseq, (void*)&hlast,
        (void*)&hb, (void*)&flags,
        (void*)&Wrx, (void*)&Wrh, (void*)&Wux, (void*)&Wuh, (void*)&Wcx, (void*)&Wch,
        (void*)&brx, (void*)&brh, (void*)&bux, (void*)&buh, (void*)&bcx, (void*)&bch };

    hipError_t err = hipLaunchCooperativeKernel((void*)gru_persistent,
                                                dim3(256), dim3(512), args, 0, stream);
    if (err != hipSuccess) {
        // Nothing was enqueued. 256 blocks at 1 block/CU on 256 CUs are
        // co-resident under a plain launch too; the flag protocol needs no
        // grid.sync, so this fallback is safe.
        (void)hipGetLastError();
        gru_persistent<<<dim3(256), dim3(512), 0, stream>>>(
            x, h0, hseq, hlast, hb, flags,
            Wrx, Wrh, Wux, Wuh, Wcx, Wch,
            brx, brh, bux, buh, bcx, bch);
    }
}